// Round 1
// baseline (1332.891 us; speedup 1.0000x reference)
//
#include <hip/hip_runtime.h>
#include <cstdint>

// MoE FFN: T=4096 tokens, D=1024, H=4096, E=8, top-2.
// Pipeline: router -> scan -> gather(compact bf16 rows) -> grouped GEMM1
// (silu(x@Wg)*(x@Wu) -> bf16 H) -> grouped GEMM2 (H@Wd, weighted atomic scatter).
// ws layout (84.0 MB total):
//   counts[8] | cursor[8] | offs[9] | te[8192] | tw[8192] | stok[8192] | sw[8192]
//   | Xg bf16[8192*1024] | H bf16[8192*4096]

#define D_MODEL 1024
#define HIDDEN  4096
#define N_EXP   8
#define T_TOK   4096
#define NSLOT   (T_TOK * 2)

typedef __attribute__((ext_vector_type(8))) short bf16x8;
typedef __attribute__((ext_vector_type(4))) float f32x4;
typedef __attribute__((ext_vector_type(8))) unsigned short ushort8;

__device__ __forceinline__ void async_ld16(const void* g, void* l) {
  auto gp = reinterpret_cast<const __attribute__((address_space(1))) void*>(
      reinterpret_cast<uintptr_t>(g));
  auto lp = reinterpret_cast<__attribute__((address_space(3))) void*>(
      reinterpret_cast<uintptr_t>(l));
  __builtin_amdgcn_global_load_lds(gp, lp, 16, 0, 0);
}

__device__ __forceinline__ unsigned short f2bf(float f) {  // RNE
  unsigned u = __builtin_bit_cast(unsigned, f);
  u += 0x7FFFu + ((u >> 16) & 1u);
  return (unsigned short)(u >> 16);
}
__device__ __forceinline__ unsigned pack2(float a, float b) {
  return (unsigned)f2bf(a) | ((unsigned)f2bf(b) << 16);
}

// ---------------- router: one wave per token ----------------
__global__ __launch_bounds__(256) void k_router(
    const float* __restrict__ x, const float* __restrict__ Wr,
    int* __restrict__ counts, int* __restrict__ te, float* __restrict__ tw) {
  int t = (blockIdx.x * 256 + threadIdx.x) >> 6;
  int lane = threadIdx.x & 63;
  const float* xr = x + (size_t)t * D_MODEL;
  float acc[N_EXP];
#pragma unroll
  for (int e = 0; e < N_EXP; e++) acc[e] = 0.f;
#pragma unroll
  for (int i = 0; i < 16; i++) {
    int k = i * 64 + lane;           // coalesced x reads
    float xv = xr[k];
    f32x4 w0 = *(const f32x4*)(Wr + k * 8);
    f32x4 w1 = *(const f32x4*)(Wr + k * 8 + 4);
#pragma unroll
    for (int e = 0; e < 4; e++) { acc[e] += xv * w0[e]; acc[4 + e] += xv * w1[e]; }
  }
#pragma unroll
  for (int e = 0; e < N_EXP; e++)
#pragma unroll
    for (int off = 32; off > 0; off >>= 1) acc[e] += __shfl_xor(acc[e], off, 64);
  // top-2 (ties -> lowest index, matching lax.top_k)
  int e0 = 0; float l0 = acc[0];
#pragma unroll
  for (int e = 1; e < N_EXP; e++) if (acc[e] > l0) { l0 = acc[e]; e0 = e; }
  int e1 = (e0 == 0) ? 1 : 0; float l1 = acc[e1];
#pragma unroll
  for (int e = 0; e < N_EXP; e++)
    if (e != e0 && acc[e] > l1) { l1 = acc[e]; e1 = e; }
  if (lane == 0) {
    float w0v = 1.f / (1.f + __expf(l1 - l0));  // = renormalized top-2 softmax
    te[2 * t] = e0; te[2 * t + 1] = e1;
    tw[2 * t] = w0v; tw[2 * t + 1] = 1.f - w0v;
    atomicAdd(&counts[e0], 1);
    atomicAdd(&counts[e1], 1);
  }
}

// ---------------- scan: exact expert offsets ----------------
__global__ void k_scan(const int* __restrict__ counts, int* __restrict__ offs,
                       int* __restrict__ cursor) {
  if (threadIdx.x == 0) {
    int s = 0;
    for (int e = 0; e < N_EXP; e++) { offs[e] = s; cursor[e] = s; s += counts[e]; }
    offs[N_EXP] = s;  // == 8192
  }
}

// ---------------- gather: compact bf16 token rows per expert ----------------
__global__ __launch_bounds__(256) void k_gather(
    const float* __restrict__ x, const int* __restrict__ te,
    const float* __restrict__ tw, int* __restrict__ cursor,
    int* __restrict__ stok, float* __restrict__ sw,
    unsigned short* __restrict__ Xg) {
  int t = (blockIdx.x * 256 + threadIdx.x) >> 6;
  int lane = threadIdx.x & 63;
  const float* xr = x + (size_t)t * D_MODEL + lane * 16;
  f32x4 v0 = *(const f32x4*)(xr);
  f32x4 v1 = *(const f32x4*)(xr + 4);
  f32x4 v2 = *(const f32x4*)(xr + 8);
  f32x4 v3 = *(const f32x4*)(xr + 12);
  ushort8 p0, p1;
#pragma unroll
  for (int i = 0; i < 4; i++) {
    p0[i] = f2bf(v0[i]); p0[4 + i] = f2bf(v1[i]);
    p1[i] = f2bf(v2[i]); p1[4 + i] = f2bf(v3[i]);
  }
#pragma unroll
  for (int j = 0; j < 2; j++) {
    int e = te[2 * t + j];
    int slot = 0;
    if (lane == 0) slot = atomicAdd(&cursor[e], 1);
    slot = __shfl(slot, 0, 64);
    if (lane == 0) { stok[slot] = t; sw[slot] = tw[2 * t + j]; }
    unsigned short* dst = Xg + (size_t)slot * D_MODEL + lane * 16;
    *(ushort8*)(dst) = p0;
    *(ushort8*)(dst + 8) = p1;
  }
}

// ---------------- grouped GEMM1: silu(X@Wg)*(X@Wu) -> H (bf16) -------------
// 128x128 tile, BK=64, 4 waves each 64x64 via 4x4 of 16x16x32 bf16 MFMA.
// LDS chunk-major: elem (row,k) at [((k>>3)*128 + row)*8 + (k&7)] -> frag
// reads are ~2-way on banks (free); A staged by 16B global_load_lds.
__global__ __launch_bounds__(256, 2) void k_gemm1(
    const unsigned short* __restrict__ Xg,
    const float* __restrict__ Wg, const float* __restrict__ Wu,
    const int* __restrict__ offs, unsigned short* __restrict__ H) {
  int bid = blockIdx.x;
  int e = bid >> 10, mt = (bid >> 5) & 31, nt = bid & 31;
  int base = offs[e];
  int ne = offs[e + 1] - base;
  if (mt * 128 >= ne) return;

  __shared__ __align__(16) unsigned short At[8 * 128 * 8];
  __shared__ __align__(16) unsigned short Bg[8 * 128 * 8];
  __shared__ __align__(16) unsigned short Bu[8 * 128 * 8];

  int tid = threadIdx.x;
  int wv = tid >> 6, lane = tid & 63;
  int quad = lane >> 4, lr = lane & 15;
  int rh = (wv >> 1) * 64, ch = (wv & 1) * 64;

  f32x4 accG[4][4], accU[4][4];
#pragma unroll
  for (int i = 0; i < 4; i++)
#pragma unroll
    for (int j = 0; j < 4; j++) {
      accG[i][j] = (f32x4){0.f, 0.f, 0.f, 0.f};
      accU[i][j] = (f32x4){0.f, 0.f, 0.f, 0.f};
    }

  const float* wgp = Wg + (size_t)e * D_MODEL * HIDDEN + (size_t)nt * 128;
  const float* wup = Wu + (size_t)e * D_MODEL * HIDDEN + (size_t)nt * 128;
  int n4 = tid >> 3;   // 0..31 -> cols n4*4..+3
  int kp0 = tid & 7;

  for (int kt = 0; kt < D_MODEL / 64; kt++) {
    // A: wave wv stages chunks 2wv,2wv+1; per instr 64 rows x 16B
#pragma unroll
    for (int s = 0; s < 4; s++) {
      int c = wv * 2 + (s >> 1);
      int h = s & 1;
      int gr = mt * 128 + h * 64 + lane;
      if (gr > ne - 1) gr = ne - 1;
      const unsigned short* gp =
          Xg + (size_t)(base + gr) * D_MODEL + kt * 64 + c * 8;
      async_ld16(gp, &At[(c * 128 + h * 64) * 8]);
    }
    // B: fp32 -> bf16 + transpose during staging (packed k-pair writes)
#pragma unroll
    for (int u = 0; u < 4; u++) {
      int kp = kp0 + u * 8;  // 0..31
      const float* pg = wgp + (size_t)(kt * 64 + kp * 2) * HIDDEN + n4 * 4;
      f32x4 g0 = *(const f32x4*)pg;
      f32x4 g1 = *(const f32x4*)(pg + HIDDEN);
      const float* pu = wup + (size_t)(kt * 64 + kp * 2) * HIDDEN + n4 * 4;
      f32x4 u0 = *(const f32x4*)pu;
      f32x4 u1 = *(const f32x4*)(pu + HIDDEN);
      int cB = kp >> 2;
      int ko = (kp & 3) * 2;
#pragma unroll
      for (int j = 0; j < 4; j++) {
        int n = n4 * 4 + j;
        *(unsigned*)&Bg[(cB * 128 + n) * 8 + ko] = pack2(g0[j], g1[j]);
        *(unsigned*)&Bu[(cB * 128 + n) * 8 + ko] = pack2(u0[j], u1[j]);
      }
    }
    __syncthreads();
#pragma unroll
    for (int ks = 0; ks < 2; ks++) {
      bf16x8 a[4], bg[4], bu[4];
#pragma unroll
      for (int i = 0; i < 4; i++)
        a[i] = *(const bf16x8*)&At[((ks * 4 + quad) * 128 + rh + i * 16 + lr) * 8];
#pragma unroll
      for (int j = 0; j < 4; j++) {
        bg[j] = *(const bf16x8*)&Bg[((ks * 4 + quad) * 128 + ch + j * 16 + lr) * 8];
        bu[j] = *(const bf16x8*)&Bu[((ks * 4 + quad) * 128 + ch + j * 16 + lr) * 8];
      }
#pragma unroll
      for (int i = 0; i < 4; i++)
#pragma unroll
        for (int j = 0; j < 4; j++) {
          accG[i][j] = __builtin_amdgcn_mfma_f32_16x16x32_bf16(a[i], bg[j], accG[i][j], 0, 0, 0);
          accU[i][j] = __builtin_amdgcn_mfma_f32_16x16x32_bf16(a[i], bu[j], accU[i][j], 0, 0, 0);
        }
    }
    __syncthreads();
  }
  // epilogue: h = silu(g)*u, bf16 store (C layout: row=quad*4+r, col=lr)
#pragma unroll
  for (int i = 0; i < 4; i++)
#pragma unroll
    for (int r = 0; r < 4; r++) {
      int grow = mt * 128 + rh + i * 16 + quad * 4 + r;
      if (grow < ne) {
        size_t rowoff = (size_t)(base + grow) * HIDDEN + (size_t)nt * 128 + ch + lr;
#pragma unroll
        for (int j = 0; j < 4; j++) {
          float g = accG[i][j][r];
          float hv = g / (1.f + __expf(-g)) * accU[i][j][r];
          H[rowoff + j * 16] = f2bf(hv);
        }
      }
    }
}

// ---------------- grouped GEMM2: (H @ Wd) * w -> atomic scatter to out ------
__global__ __launch_bounds__(256, 2) void k_gemm2(
    const unsigned short* __restrict__ H, const float* __restrict__ Wd,
    const int* __restrict__ offs, const int* __restrict__ stok,
    const float* __restrict__ sw, float* __restrict__ out) {
  int bid = blockIdx.x;
  int e = bid >> 8, mt = (bid >> 3) & 31, nt = bid & 7;
  int base = offs[e];
  int ne = offs[e + 1] - base;
  if (mt * 128 >= ne) return;

  __shared__ __align__(16) unsigned short At[8 * 128 * 8];
  __shared__ __align__(16) unsigned short Bd[8 * 128 * 8];

  int tid = threadIdx.x;
  int wv = tid >> 6, lane = tid & 63;
  int quad = lane >> 4, lr = lane & 15;
  int rh = (wv >> 1) * 64, ch = (wv & 1) * 64;

  f32x4 acc[4][4];
#pragma unroll
  for (int i = 0; i < 4; i++)
#pragma unroll
    for (int j = 0; j < 4; j++) acc[i][j] = (f32x4){0.f, 0.f, 0.f, 0.f};

  const float* wdp = Wd + (size_t)e * HIDDEN * D_MODEL + (size_t)nt * 128;
  int n4 = tid >> 3;
  int kp0 = tid & 7;

  for (int kt = 0; kt < HIDDEN / 64; kt++) {
#pragma unroll
    for (int s = 0; s < 4; s++) {
      int c = wv * 2 + (s >> 1);
      int h = s & 1;
      int gr = mt * 128 + h * 64 + lane;
      if (gr > ne - 1) gr = ne - 1;
      const unsigned short* gp =
          H + (size_t)(base + gr) * HIDDEN + kt * 64 + c * 8;
      async_ld16(gp, &At[(c * 128 + h * 64) * 8]);
    }
#pragma unroll
    for (int u = 0; u < 4; u++) {
      int kp = kp0 + u * 8;
      const float* pd = wdp + (size_t)(kt * 64 + kp * 2) * D_MODEL + n4 * 4;
      f32x4 d0 = *(const f32x4*)pd;
      f32x4 d1 = *(const f32x4*)(pd + D_MODEL);
      int cB = kp >> 2;
      int ko = (kp & 3) * 2;
#pragma unroll
      for (int j = 0; j < 4; j++)
        *(unsigned*)&Bd[(cB * 128 + n4 * 4 + j) * 8 + ko] = pack2(d0[j], d1[j]);
    }
    __syncthreads();
#pragma unroll
    for (int ks = 0; ks < 2; ks++) {
      bf16x8 a[4], b[4];
#pragma unroll
      for (int i = 0; i < 4; i++)
        a[i] = *(const bf16x8*)&At[((ks * 4 + quad) * 128 + rh + i * 16 + lr) * 8];
#pragma unroll
      for (int j = 0; j < 4; j++)
        b[j] = *(const bf16x8*)&Bd[((ks * 4 + quad) * 128 + ch + j * 16 + lr) * 8];
#pragma unroll
      for (int i = 0; i < 4; i++)
#pragma unroll
        for (int j = 0; j < 4; j++)
          acc[i][j] = __builtin_amdgcn_mfma_f32_16x16x32_bf16(a[i], b[j], acc[i][j], 0, 0, 0);
    }
    __syncthreads();
  }
#pragma unroll
  for (int i = 0; i < 4; i++)
#pragma unroll
    for (int r = 0; r < 4; r++) {
      int grow = mt * 128 + rh + i * 16 + quad * 4 + r;
      if (grow < ne) {
        int slot = base + grow;
        int t = stok[slot];
        float w = sw[slot];
        float* op = out + (size_t)t * D_MODEL + nt * 128 + ch + lr;
#pragma unroll
        for (int j = 0; j < 4; j++)
          unsafeAtomicAdd(op + j * 16, acc[i][j][r] * w);
      }
    }
}

extern "C" void kernel_launch(void* const* d_in, const int* in_sizes, int n_in,
                              void* d_out, int out_size, void* d_ws, size_t ws_size,
                              hipStream_t stream) {
  const float* x  = (const float*)d_in[0];
  const float* Wg = (const float*)d_in[1];
  const float* Wu = (const float*)d_in[2];
  const float* Wd = (const float*)d_in[3];
  const float* Wr = (const float*)d_in[4];
  float* out = (float*)d_out;

  int* counts = (int*)d_ws;            // [8]
  int* cursor = counts + 8;            // [8]
  int* offs   = counts + 16;           // [9]
  int* te     = counts + 32;           // [2*T]
  float* tw   = (float*)(te + NSLOT);  // [2*T]
  int* stok   = (int*)(tw + NSLOT);    // [2*T]
  float* sw   = (float*)(stok + NSLOT);// [2*T]
  unsigned short* Xg = (unsigned short*)(sw + NSLOT);   // [8192*1024] bf16
  unsigned short* H  = Xg + (size_t)NSLOT * D_MODEL;    // [8192*4096] bf16

  size_t need = (size_t)((char*)(H + (size_t)NSLOT * HIDDEN) - (char*)d_ws);
  hipMemsetAsync(out, 0, (size_t)out_size * sizeof(float), stream);
  if (ws_size < need) return;  // ws too small: leaves zeros (clean absmax fail)

  hipMemsetAsync(counts, 0, 64, stream);
  k_router<<<T_TOK / 4, 256, 0, stream>>>(x, Wr, counts, te, tw);
  k_scan<<<1, 64, 0, stream>>>(counts, offs, cursor);
  k_gather<<<T_TOK / 4, 256, 0, stream>>>(x, te, tw, cursor, stok, sw, Xg);
  k_gemm1<<<N_EXP * 32 * 32, 256, 0, stream>>>(Xg, Wg, Wu, offs, H);
  k_gemm2<<<N_EXP * 32 * 8, 256, 0, stream>>>(H, Wd, offs, stok, sw, out);
}

// Round 2
// 1212.723 us; speedup vs baseline: 1.0991x; 1.0991x over previous
//
#include <hip/hip_runtime.h>
#include <cstdint>

// MoE FFN: T=4096 tokens, D=1024, H=4096, E=8, top-2.
// Fast path (needs ~276 MB ws): router -> scan -> gather -> transpose+cast
// weights to bf16 [e][n][k] -> m97-style grouped GEMMs (all operands staged
// via 16B global_load_lds, no VALU packing).
// Fallback path (84 MB ws): round-1 kernels (per-tile fp32 transpose in LDS).

#define D_MODEL 1024
#define HIDDEN  4096
#define N_EXP   8
#define T_TOK   4096
#define NSLOT   (T_TOK * 2)

typedef __attribute__((ext_vector_type(8))) short bf16x8;
typedef __attribute__((ext_vector_type(4))) float f32x4;
typedef __attribute__((ext_vector_type(8))) unsigned short ushort8;

__device__ __forceinline__ void async_ld16(const void* g, void* l) {
  auto gp = reinterpret_cast<const __attribute__((address_space(1))) void*>(
      reinterpret_cast<uintptr_t>(g));
  auto lp = reinterpret_cast<__attribute__((address_space(3))) void*>(
      reinterpret_cast<uintptr_t>(l));
  __builtin_amdgcn_global_load_lds(gp, lp, 16, 0, 0);
}

__device__ __forceinline__ unsigned short f2bf(float f) {  // RNE
  unsigned u = __builtin_bit_cast(unsigned, f);
  u += 0x7FFFu + ((u >> 16) & 1u);
  return (unsigned short)(u >> 16);
}
__device__ __forceinline__ unsigned pack2(float a, float b) {
  return (unsigned)f2bf(a) | ((unsigned)f2bf(b) << 16);
}

// ---------------- router: one wave per token ----------------
__global__ __launch_bounds__(256) void k_router(
    const float* __restrict__ x, const float* __restrict__ Wr,
    int* __restrict__ counts, int* __restrict__ te, float* __restrict__ tw) {
  int t = (blockIdx.x * 256 + threadIdx.x) >> 6;
  int lane = threadIdx.x & 63;
  const float* xr = x + (size_t)t * D_MODEL;
  float acc[N_EXP];
#pragma unroll
  for (int e = 0; e < N_EXP; e++) acc[e] = 0.f;
#pragma unroll
  for (int i = 0; i < 16; i++) {
    int k = i * 64 + lane;
    float xv = xr[k];
    f32x4 w0 = *(const f32x4*)(Wr + k * 8);
    f32x4 w1 = *(const f32x4*)(Wr + k * 8 + 4);
#pragma unroll
    for (int e = 0; e < 4; e++) { acc[e] += xv * w0[e]; acc[4 + e] += xv * w1[e]; }
  }
#pragma unroll
  for (int e = 0; e < N_EXP; e++)
#pragma unroll
    for (int off = 32; off > 0; off >>= 1) acc[e] += __shfl_xor(acc[e], off, 64);
  int e0 = 0; float l0 = acc[0];
#pragma unroll
  for (int e = 1; e < N_EXP; e++) if (acc[e] > l0) { l0 = acc[e]; e0 = e; }
  int e1 = (e0 == 0) ? 1 : 0; float l1 = acc[e1];
#pragma unroll
  for (int e = 0; e < N_EXP; e++)
    if (e != e0 && acc[e] > l1) { l1 = acc[e]; e1 = e; }
  if (lane == 0) {
    float w0v = 1.f / (1.f + __expf(l1 - l0));
    te[2 * t] = e0; te[2 * t + 1] = e1;
    tw[2 * t] = w0v; tw[2 * t + 1] = 1.f - w0v;
    atomicAdd(&counts[e0], 1);
    atomicAdd(&counts[e1], 1);
  }
}

__global__ void k_scan(const int* __restrict__ counts, int* __restrict__ offs,
                       int* __restrict__ cursor) {
  if (threadIdx.x == 0) {
    int s = 0;
    for (int e = 0; e < N_EXP; e++) { offs[e] = s; cursor[e] = s; s += counts[e]; }
    offs[N_EXP] = s;
  }
}

// ---------------- gather: compact bf16 token rows per expert ----------------
__global__ __launch_bounds__(256) void k_gather(
    const float* __restrict__ x, const int* __restrict__ te,
    const float* __restrict__ tw, int* __restrict__ cursor,
    int* __restrict__ stok, float* __restrict__ sw,
    unsigned short* __restrict__ Xg) {
  int t = (blockIdx.x * 256 + threadIdx.x) >> 6;
  int lane = threadIdx.x & 63;
  const float* xr = x + (size_t)t * D_MODEL + lane * 16;
  f32x4 v0 = *(const f32x4*)(xr);
  f32x4 v1 = *(const f32x4*)(xr + 4);
  f32x4 v2 = *(const f32x4*)(xr + 8);
  f32x4 v3 = *(const f32x4*)(xr + 12);
  ushort8 p0, p1;
#pragma unroll
  for (int i = 0; i < 4; i++) {
    p0[i] = f2bf(v0[i]); p0[4 + i] = f2bf(v1[i]);
    p1[i] = f2bf(v2[i]); p1[4 + i] = f2bf(v3[i]);
  }
#pragma unroll
  for (int j = 0; j < 2; j++) {
    int e = te[2 * t + j];
    int slot = 0;
    if (lane == 0) slot = atomicAdd(&cursor[e], 1);
    slot = __shfl(slot, 0, 64);
    if (lane == 0) { stok[slot] = t; sw[slot] = tw[2 * t + j]; }
    unsigned short* dst = Xg + (size_t)slot * D_MODEL + lane * 16;
    *(ushort8*)(dst) = p0;
    *(ushort8*)(dst + 8) = p1;
  }
}

// ---------------- transpose+cast: W[e][K][N] f32 -> WT[e][N][K] bf16 --------
// Reads coalesced (lanes span n); writes 16B/lane k-contiguous, L2 merges
// partial lines (block covers k0..k0+31 for same n-range -> full 64B lines).
__global__ __launch_bounds__(256) void k_transpose(
    const float* __restrict__ W, unsigned short* __restrict__ WT,
    int K, int N) {
  int e = blockIdx.z;
  int n = blockIdx.x * 256 + threadIdx.x;
  int k0 = blockIdx.y * 32;
  const float* src = W + (size_t)e * K * N + n;
  unsigned short* dst = WT + (size_t)e * N * K + (size_t)n * K + k0;
#pragma unroll
  for (int i = 0; i < 4; i++) {
    ushort8 p;
#pragma unroll
    for (int j = 0; j < 8; j++)
      p[j] = f2bf(src[(size_t)(k0 + i * 8 + j) * N]);
    *(ushort8*)(dst + i * 8) = p;
  }
}

// ============================ FAST-PATH GEMMS ==============================
// m97-style: 128x128 tile, BK=64, 4 waves x (64x64 via 4x4 16x16x32 MFMA).
// LDS chunk-major: elem (row,k) at [((k>>3)*128+row)*8 + (k&7)]; A and B both
// staged with 16B global_load_lds (wave-uniform base + lane*16).

__global__ __launch_bounds__(256, 2) void k_gemm1_fast(
    const unsigned short* __restrict__ Xg,
    const unsigned short* __restrict__ WgT,
    const unsigned short* __restrict__ WuT,
    const int* __restrict__ offs, unsigned short* __restrict__ H) {
  int bid = blockIdx.x;
  int e = bid >> 10, mt = (bid >> 5) & 31, nt = bid & 31;
  int base = offs[e];
  int ne = offs[e + 1] - base;
  if (mt * 128 >= ne) return;

  __shared__ __align__(16) unsigned short At[8 * 128 * 8];
  __shared__ __align__(16) unsigned short Bg[8 * 128 * 8];
  __shared__ __align__(16) unsigned short Bu[8 * 128 * 8];

  int tid = threadIdx.x;
  int wv = tid >> 6, lane = tid & 63;
  int quad = lane >> 4, lr = lane & 15;
  int rh = (wv >> 1) * 64, ch = (wv & 1) * 64;

  f32x4 accG[4][4], accU[4][4];
#pragma unroll
  for (int i = 0; i < 4; i++)
#pragma unroll
    for (int j = 0; j < 4; j++) {
      accG[i][j] = (f32x4){0.f, 0.f, 0.f, 0.f};
      accU[i][j] = (f32x4){0.f, 0.f, 0.f, 0.f};
    }

  const unsigned short* bgp = WgT + (size_t)e * D_MODEL * HIDDEN +
                              (size_t)(nt * 128) * D_MODEL;
  const unsigned short* bup = WuT + (size_t)e * D_MODEL * HIDDEN +
                              (size_t)(nt * 128) * D_MODEL;

  for (int kt = 0; kt < D_MODEL / 64; kt++) {
#pragma unroll
    for (int s = 0; s < 4; s++) {
      int c = wv * 2 + (s >> 1);
      int h = s & 1;
      int gr = mt * 128 + h * 64 + lane;
      if (gr > ne - 1) gr = ne - 1;
      async_ld16(Xg + (size_t)(base + gr) * D_MODEL + kt * 64 + c * 8,
                 &At[(c * 128 + h * 64) * 8]);
    }
#pragma unroll
    for (int s = 0; s < 4; s++) {
      int c = wv * 2 + (s >> 1);
      int h = s & 1;
      int n = h * 64 + lane;
      async_ld16(bgp + (size_t)n * D_MODEL + kt * 64 + c * 8,
                 &Bg[(c * 128 + h * 64) * 8]);
      async_ld16(bup + (size_t)n * D_MODEL + kt * 64 + c * 8,
                 &Bu[(c * 128 + h * 64) * 8]);
    }
    __syncthreads();
#pragma unroll
    for (int ks = 0; ks < 2; ks++) {
      bf16x8 a[4], bg[4], bu[4];
#pragma unroll
      for (int i = 0; i < 4; i++)
        a[i] = *(const bf16x8*)&At[((ks * 4 + quad) * 128 + rh + i * 16 + lr) * 8];
#pragma unroll
      for (int j = 0; j < 4; j++) {
        bg[j] = *(const bf16x8*)&Bg[((ks * 4 + quad) * 128 + ch + j * 16 + lr) * 8];
        bu[j] = *(const bf16x8*)&Bu[((ks * 4 + quad) * 128 + ch + j * 16 + lr) * 8];
      }
#pragma unroll
      for (int i = 0; i < 4; i++)
#pragma unroll
        for (int j = 0; j < 4; j++) {
          accG[i][j] = __builtin_amdgcn_mfma_f32_16x16x32_bf16(a[i], bg[j], accG[i][j], 0, 0, 0);
          accU[i][j] = __builtin_amdgcn_mfma_f32_16x16x32_bf16(a[i], bu[j], accU[i][j], 0, 0, 0);
        }
    }
    __syncthreads();
  }
#pragma unroll
  for (int i = 0; i < 4; i++)
#pragma unroll
    for (int r = 0; r < 4; r++) {
      int grow = mt * 128 + rh + i * 16 + quad * 4 + r;
      if (grow < ne) {
        size_t rowoff = (size_t)(base + grow) * HIDDEN + (size_t)nt * 128 + ch + lr;
#pragma unroll
        for (int j = 0; j < 4; j++) {
          float g = accG[i][j][r];
          float hv = g / (1.f + __expf(-g)) * accU[i][j][r];
          H[rowoff + j * 16] = f2bf(hv);
        }
      }
    }
}

__global__ __launch_bounds__(256, 2) void k_gemm2_fast(
    const unsigned short* __restrict__ H,
    const unsigned short* __restrict__ WdT,
    const int* __restrict__ offs, const int* __restrict__ stok,
    const float* __restrict__ sw, float* __restrict__ out) {
  int bid = blockIdx.x;
  int e = bid >> 8, mt = (bid >> 3) & 31, nt = bid & 7;
  int base = offs[e];
  int ne = offs[e + 1] - base;
  if (mt * 128 >= ne) return;

  __shared__ __align__(16) unsigned short At[8 * 128 * 8];
  __shared__ __align__(16) unsigned short Bd[8 * 128 * 8];

  int tid = threadIdx.x;
  int wv = tid >> 6, lane = tid & 63;
  int quad = lane >> 4, lr = lane & 15;
  int rh = (wv >> 1) * 64, ch = (wv & 1) * 64;

  f32x4 acc[4][4];
#pragma unroll
  for (int i = 0; i < 4; i++)
#pragma unroll
    for (int j = 0; j < 4; j++) acc[i][j] = (f32x4){0.f, 0.f, 0.f, 0.f};

  const unsigned short* bdp = WdT + (size_t)e * HIDDEN * D_MODEL +
                              (size_t)(nt * 128) * HIDDEN;

  for (int kt = 0; kt < HIDDEN / 64; kt++) {
#pragma unroll
    for (int s = 0; s < 4; s++) {
      int c = wv * 2 + (s >> 1);
      int h = s & 1;
      int gr = mt * 128 + h * 64 + lane;
      if (gr > ne - 1) gr = ne - 1;
      async_ld16(H + (size_t)(base + gr) * HIDDEN + kt * 64 + c * 8,
                 &At[(c * 128 + h * 64) * 8]);
    }
#pragma unroll
    for (int s = 0; s < 4; s++) {
      int c = wv * 2 + (s >> 1);
      int h = s & 1;
      int n = h * 64 + lane;
      async_ld16(bdp + (size_t)n * HIDDEN + kt * 64 + c * 8,
                 &Bd[(c * 128 + h * 64) * 8]);
    }
    __syncthreads();
#pragma unroll
    for (int ks = 0; ks < 2; ks++) {
      bf16x8 a[4], b[4];
#pragma unroll
      for (int i = 0; i < 4; i++)
        a[i] = *(const bf16x8*)&At[((ks * 4 + quad) * 128 + rh + i * 16 + lr) * 8];
#pragma unroll
      for (int j = 0; j < 4; j++)
        b[j] = *(const bf16x8*)&Bd[((ks * 4 + quad) * 128 + ch + j * 16 + lr) * 8];
#pragma unroll
      for (int i = 0; i < 4; i++)
#pragma unroll
        for (int j = 0; j < 4; j++)
          acc[i][j] = __builtin_amdgcn_mfma_f32_16x16x32_bf16(a[i], b[j], acc[i][j], 0, 0, 0);
    }
    __syncthreads();
  }
#pragma unroll
  for (int i = 0; i < 4; i++)
#pragma unroll
    for (int r = 0; r < 4; r++) {
      int grow = mt * 128 + rh + i * 16 + quad * 4 + r;
      if (grow < ne) {
        int slot = base + grow;
        int t = stok[slot];
        float w = sw[slot];
        float* op = out + (size_t)t * D_MODEL + nt * 128 + ch + lr;
#pragma unroll
        for (int j = 0; j < 4; j++)
          unsafeAtomicAdd(op + j * 16, acc[i][j][r] * w);
      }
    }
}

// ============================ FALLBACK GEMMS (round 1) ======================
__global__ __launch_bounds__(256, 2) void k_gemm1(
    const unsigned short* __restrict__ Xg,
    const float* __restrict__ Wg, const float* __restrict__ Wu,
    const int* __restrict__ offs, unsigned short* __restrict__ H) {
  int bid = blockIdx.x;
  int e = bid >> 10, mt = (bid >> 5) & 31, nt = bid & 31;
  int base = offs[e];
  int ne = offs[e + 1] - base;
  if (mt * 128 >= ne) return;

  __shared__ __align__(16) unsigned short At[8 * 128 * 8];
  __shared__ __align__(16) unsigned short Bg[8 * 128 * 8];
  __shared__ __align__(16) unsigned short Bu[8 * 128 * 8];

  int tid = threadIdx.x;
  int wv = tid >> 6, lane = tid & 63;
  int quad = lane >> 4, lr = lane & 15;
  int rh = (wv >> 1) * 64, ch = (wv & 1) * 64;

  f32x4 accG[4][4], accU[4][4];
#pragma unroll
  for (int i = 0; i < 4; i++)
#pragma unroll
    for (int j = 0; j < 4; j++) {
      accG[i][j] = (f32x4){0.f, 0.f, 0.f, 0.f};
      accU[i][j] = (f32x4){0.f, 0.f, 0.f, 0.f};
    }

  const float* wgp = Wg + (size_t)e * D_MODEL * HIDDEN + (size_t)nt * 128;
  const float* wup = Wu + (size_t)e * D_MODEL * HIDDEN + (size_t)nt * 128;
  int n4 = tid >> 3;
  int kp0 = tid & 7;

  for (int kt = 0; kt < D_MODEL / 64; kt++) {
#pragma unroll
    for (int s = 0; s < 4; s++) {
      int c = wv * 2 + (s >> 1);
      int h = s & 1;
      int gr = mt * 128 + h * 64 + lane;
      if (gr > ne - 1) gr = ne - 1;
      async_ld16(Xg + (size_t)(base + gr) * D_MODEL + kt * 64 + c * 8,
                 &At[(c * 128 + h * 64) * 8]);
    }
#pragma unroll
    for (int u = 0; u < 4; u++) {
      int kp = kp0 + u * 8;
      const float* pg = wgp + (size_t)(kt * 64 + kp * 2) * HIDDEN + n4 * 4;
      f32x4 g0 = *(const f32x4*)pg;
      f32x4 g1 = *(const f32x4*)(pg + HIDDEN);
      const float* pu = wup + (size_t)(kt * 64 + kp * 2) * HIDDEN + n4 * 4;
      f32x4 u0 = *(const f32x4*)pu;
      f32x4 u1 = *(const f32x4*)(pu + HIDDEN);
      int cB = kp >> 2;
      int ko = (kp & 3) * 2;
#pragma unroll
      for (int j = 0; j < 4; j++) {
        int n = n4 * 4 + j;
        *(unsigned*)&Bg[(cB * 128 + n) * 8 + ko] = pack2(g0[j], g1[j]);
        *(unsigned*)&Bu[(cB * 128 + n) * 8 + ko] = pack2(u0[j], u1[j]);
      }
    }
    __syncthreads();
#pragma unroll
    for (int ks = 0; ks < 2; ks++) {
      bf16x8 a[4], bg[4], bu[4];
#pragma unroll
      for (int i = 0; i < 4; i++)
        a[i] = *(const bf16x8*)&At[((ks * 4 + quad) * 128 + rh + i * 16 + lr) * 8];
#pragma unroll
      for (int j = 0; j < 4; j++) {
        bg[j] = *(const bf16x8*)&Bg[((ks * 4 + quad) * 128 + ch + j * 16 + lr) * 8];
        bu[j] = *(const bf16x8*)&Bu[((ks * 4 + quad) * 128 + ch + j * 16 + lr) * 8];
      }
#pragma unroll
      for (int i = 0; i < 4; i++)
#pragma unroll
        for (int j = 0; j < 4; j++) {
          accG[i][j] = __builtin_amdgcn_mfma_f32_16x16x32_bf16(a[i], bg[j], accG[i][j], 0, 0, 0);
          accU[i][j] = __builtin_amdgcn_mfma_f32_16x16x32_bf16(a[i], bu[j], accU[i][j], 0, 0, 0);
        }
    }
    __syncthreads();
  }
#pragma unroll
  for (int i = 0; i < 4; i++)
#pragma unroll
    for (int r = 0; r < 4; r++) {
      int grow = mt * 128 + rh + i * 16 + quad * 4 + r;
      if (grow < ne) {
        size_t rowoff = (size_t)(base + grow) * HIDDEN + (size_t)nt * 128 + ch + lr;
#pragma unroll
        for (int j = 0; j < 4; j++) {
          float g = accG[i][j][r];
          float hv = g / (1.f + __expf(-g)) * accU[i][j][r];
          H[rowoff + j * 16] = f2bf(hv);
        }
      }
    }
}

__global__ __launch_bounds__(256, 2) void k_gemm2(
    const unsigned short* __restrict__ H, const float* __restrict__ Wd,
    const int* __restrict__ offs, const int* __restrict__ stok,
    const float* __restrict__ sw, float* __restrict__ out) {
  int bid = blockIdx.x;
  int e = bid >> 8, mt = (bid >> 3) & 31, nt = bid & 7;
  int base = offs[e];
  int ne = offs[e + 1] - base;
  if (mt * 128 >= ne) return;

  __shared__ __align__(16) unsigned short At[8 * 128 * 8];
  __shared__ __align__(16) unsigned short Bd[8 * 128 * 8];

  int tid = threadIdx.x;
  int wv = tid >> 6, lane = tid & 63;
  int quad = lane >> 4, lr = lane & 15;
  int rh = (wv >> 1) * 64, ch = (wv & 1) * 64;

  f32x4 acc[4][4];
#pragma unroll
  for (int i = 0; i < 4; i++)
#pragma unroll
    for (int j = 0; j < 4; j++) acc[i][j] = (f32x4){0.f, 0.f, 0.f, 0.f};

  const float* wdp = Wd + (size_t)e * HIDDEN * D_MODEL + (size_t)nt * 128;
  int n4 = tid >> 3;
  int kp0 = tid & 7;

  for (int kt = 0; kt < HIDDEN / 64; kt++) {
#pragma unroll
    for (int s = 0; s < 4; s++) {
      int c = wv * 2 + (s >> 1);
      int h = s & 1;
      int gr = mt * 128 + h * 64 + lane;
      if (gr > ne - 1) gr = ne - 1;
      async_ld16(H + (size_t)(base + gr) * HIDDEN + kt * 64 + c * 8,
                 &At[(c * 128 + h * 64) * 8]);
    }
#pragma unroll
    for (int u = 0; u < 4; u++) {
      int kp = kp0 + u * 8;
      const float* pd = wdp + (size_t)(kt * 64 + kp * 2) * D_MODEL + n4 * 4;
      f32x4 d0 = *(const f32x4*)pd;
      f32x4 d1 = *(const f32x4*)(pd + D_MODEL);
      int cB = kp >> 2;
      int ko = (kp & 3) * 2;
#pragma unroll
      for (int j = 0; j < 4; j++)
        *(unsigned*)&Bd[(cB * 128 + n4 * 4 + j) * 8 + ko] = pack2(d0[j], d1[j]);
    }
    __syncthreads();
#pragma unroll
    for (int ks = 0; ks < 2; ks++) {
      bf16x8 a[4], b[4];
#pragma unroll
      for (int i = 0; i < 4; i++)
        a[i] = *(const bf16x8*)&At[((ks * 4 + quad) * 128 + rh + i * 16 + lr) * 8];
#pragma unroll
      for (int j = 0; j < 4; j++)
        b[j] = *(const bf16x8*)&Bd[((ks * 4 + quad) * 128 + ch + j * 16 + lr) * 8];
#pragma unroll
      for (int i = 0; i < 4; i++)
#pragma unroll
        for (int j = 0; j < 4; j++)
          acc[i][j] = __builtin_amdgcn_mfma_f32_16x16x32_bf16(a[i], b[j], acc[i][j], 0, 0, 0);
    }
    __syncthreads();
  }
#pragma unroll
  for (int i = 0; i < 4; i++)
#pragma unroll
    for (int r = 0; r < 4; r++) {
      int grow = mt * 128 + rh + i * 16 + quad * 4 + r;
      if (grow < ne) {
        int slot = base + grow;
        int t = stok[slot];
        float w = sw[slot];
        float* op = out + (size_t)t * D_MODEL + nt * 128 + ch + lr;
#pragma unroll
        for (int j = 0; j < 4; j++)
          unsafeAtomicAdd(op + j * 16, acc[i][j][r] * w);
      }
    }
}

extern "C" void kernel_launch(void* const* d_in, const int* in_sizes, int n_in,
                              void* d_out, int out_size, void* d_ws, size_t ws_size,
                              hipStream_t stream) {
  const float* x  = (const float*)d_in[0];
  const float* Wg = (const float*)d_in[1];
  const float* Wu = (const float*)d_in[2];
  const float* Wd = (const float*)d_in[3];
  const float* Wr = (const float*)d_in[4];
  float* out = (float*)d_out;

  int* counts = (int*)d_ws;            // [8]
  int* cursor = counts + 8;            // [8]
  int* offs   = counts + 16;           // [9]
  int* te     = counts + 32;           // [2*T]
  float* tw   = (float*)(te + NSLOT);  // [2*T]
  int* stok   = (int*)(tw + NSLOT);    // [2*T]
  float* sw   = (float*)(stok + NSLOT);// [2*T]
  unsigned short* Xg = (unsigned short*)(sw + NSLOT);   // [8192*1024] bf16
  unsigned short* H  = Xg + (size_t)NSLOT * D_MODEL;    // [8192*4096] bf16
  unsigned short* WgT = H + (size_t)NSLOT * HIDDEN;     // [8*4096*1024] bf16
  unsigned short* WuT = WgT + (size_t)N_EXP * D_MODEL * HIDDEN;
  unsigned short* WdT = WuT + (size_t)N_EXP * D_MODEL * HIDDEN;

  size_t need_slow = (size_t)((char*)WgT - (char*)d_ws);
  size_t need_fast = (size_t)((char*)(WdT + (size_t)N_EXP * HIDDEN * D_MODEL) -
                              (char*)d_ws);

  hipMemsetAsync(out, 0, (size_t)out_size * sizeof(float), stream);
  if (ws_size < need_slow) return;  // clean absmax fail

  hipMemsetAsync(counts, 0, 64, stream);
  k_router<<<T_TOK / 4, 256, 0, stream>>>(x, Wr, counts, te, tw);
  k_scan<<<1, 64, 0, stream>>>(counts, offs, cursor);
  k_gather<<<T_TOK / 4, 256, 0, stream>>>(x, te, tw, cursor, stok, sw, Xg);

  if (ws_size >= need_fast) {
    k_transpose<<<dim3(HIDDEN / 256, D_MODEL / 32, N_EXP), 256, 0, stream>>>(
        Wg, WgT, D_MODEL, HIDDEN);
    k_transpose<<<dim3(HIDDEN / 256, D_MODEL / 32, N_EXP), 256, 0, stream>>>(
        Wu, WuT, D_MODEL, HIDDEN);
    k_transpose<<<dim3(D_MODEL / 256, HIDDEN / 32, N_EXP), 256, 0, stream>>>(
        Wd, WdT, HIDDEN, D_MODEL);
    k_gemm1_fast<<<N_EXP * 32 * 32, 256, 0, stream>>>(Xg, WgT, WuT, offs, H);
    k_gemm2_fast<<<N_EXP * 32 * 8, 256, 0, stream>>>(H, WdT, offs, stok, sw, out);
  } else {
    k_gemm1<<<N_EXP * 32 * 32, 256, 0, stream>>>(Xg, Wg, Wu, offs, H);
    k_gemm2<<<N_EXP * 32 * 8, 256, 0, stream>>>(H, Wd, offs, stok, sw, out);
  }
}

// Round 3
// 1059.681 us; speedup vs baseline: 1.2578x; 1.1444x over previous
//
#include <hip/hip_runtime.h>
#include <cstdint>

// MoE FFN: T=4096 tokens, D=1024, H=4096, E=8, top-2.
// router -> scan(+tile worklist) -> gather -> LDS-tiled transpose+cast of
// weights to bf16 [e][n][k] -> grouped GEMM1 (worklist) -> grouped GEMM2
// (worklist + split-K=4, atomic scatter epilogue).

#define D_MODEL 1024
#define HIDDEN  4096
#define N_EXP   8
#define T_TOK   4096
#define NSLOT   (T_TOK * 2)
#define MAXTILE 72   // max sum_e ceil(ne/128) = 64 + 7, padded

typedef __attribute__((ext_vector_type(8))) short bf16x8;
typedef __attribute__((ext_vector_type(4))) float f32x4;
typedef __attribute__((ext_vector_type(8))) unsigned short ushort8;
typedef __attribute__((ext_vector_type(4))) unsigned u32x4;

__device__ __forceinline__ void async_ld16(const void* g, void* l) {
  auto gp = reinterpret_cast<const __attribute__((address_space(1))) void*>(
      reinterpret_cast<uintptr_t>(g));
  auto lp = reinterpret_cast<__attribute__((address_space(3))) void*>(
      reinterpret_cast<uintptr_t>(l));
  __builtin_amdgcn_global_load_lds(gp, lp, 16, 0, 0);
}

__device__ __forceinline__ unsigned short f2bf(float f) {  // RNE
  unsigned u = __builtin_bit_cast(unsigned, f);
  u += 0x7FFFu + ((u >> 16) & 1u);
  return (unsigned short)(u >> 16);
}
__device__ __forceinline__ unsigned pack2(float a, float b) {
  return (unsigned)f2bf(a) | ((unsigned)f2bf(b) << 16);
}

// ---------------- router: one wave per token ----------------
__global__ __launch_bounds__(256) void k_router(
    const float* __restrict__ x, const float* __restrict__ Wr,
    int* __restrict__ counts, int* __restrict__ te, float* __restrict__ tw) {
  int t = (blockIdx.x * 256 + threadIdx.x) >> 6;
  int lane = threadIdx.x & 63;
  const float* xr = x + (size_t)t * D_MODEL;
  float acc[N_EXP];
#pragma unroll
  for (int e = 0; e < N_EXP; e++) acc[e] = 0.f;
#pragma unroll
  for (int i = 0; i < 16; i++) {
    int k = i * 64 + lane;
    float xv = xr[k];
    f32x4 w0 = *(const f32x4*)(Wr + k * 8);
    f32x4 w1 = *(const f32x4*)(Wr + k * 8 + 4);
#pragma unroll
    for (int e = 0; e < 4; e++) { acc[e] += xv * w0[e]; acc[4 + e] += xv * w1[e]; }
  }
#pragma unroll
  for (int e = 0; e < N_EXP; e++)
#pragma unroll
    for (int off = 32; off > 0; off >>= 1) acc[e] += __shfl_xor(acc[e], off, 64);
  int e0 = 0; float l0 = acc[0];
#pragma unroll
  for (int e = 1; e < N_EXP; e++) if (acc[e] > l0) { l0 = acc[e]; e0 = e; }
  int e1 = (e0 == 0) ? 1 : 0; float l1 = acc[e1];
#pragma unroll
  for (int e = 0; e < N_EXP; e++)
    if (e != e0 && acc[e] > l1) { l1 = acc[e]; e1 = e; }
  if (lane == 0) {
    float w0v = 1.f / (1.f + __expf(l1 - l0));
    te[2 * t] = e0; te[2 * t + 1] = e1;
    tw[2 * t] = w0v; tw[2 * t + 1] = 1.f - w0v;
    atomicAdd(&counts[e0], 1);
    atomicAdd(&counts[e1], 1);
  }
}

// ---------------- scan: expert offsets + tile worklist ----------------
__global__ void k_scan(const int* __restrict__ counts, int* __restrict__ offs,
                       int* __restrict__ cursor, int* __restrict__ tiles,
                       int* __restrict__ ntiles) {
  if (threadIdx.x == 0) {
    int s = 0, nt = 0;
    for (int e = 0; e < N_EXP; e++) {
      offs[e] = s; cursor[e] = s;
      int c = counts[e];
      for (int mt = 0; mt * 128 < c; mt++) tiles[nt++] = e | (mt << 8);
      s += c;
    }
    offs[N_EXP] = s;
    *ntiles = nt;
  }
}

// ---------------- gather: compact bf16 token rows per expert ----------------
__global__ __launch_bounds__(256) void k_gather(
    const float* __restrict__ x, const int* __restrict__ te,
    const float* __restrict__ tw, int* __restrict__ cursor,
    int* __restrict__ stok, float* __restrict__ sw,
    unsigned short* __restrict__ Xg) {
  int t = (blockIdx.x * 256 + threadIdx.x) >> 6;
  int lane = threadIdx.x & 63;
  const float* xr = x + (size_t)t * D_MODEL + lane * 16;
  f32x4 v0 = *(const f32x4*)(xr);
  f32x4 v1 = *(const f32x4*)(xr + 4);
  f32x4 v2 = *(const f32x4*)(xr + 8);
  f32x4 v3 = *(const f32x4*)(xr + 12);
  ushort8 p0, p1;
#pragma unroll
  for (int i = 0; i < 4; i++) {
    p0[i] = f2bf(v0[i]); p0[4 + i] = f2bf(v1[i]);
    p1[i] = f2bf(v2[i]); p1[4 + i] = f2bf(v3[i]);
  }
#pragma unroll
  for (int j = 0; j < 2; j++) {
    int e = te[2 * t + j];
    int slot = 0;
    if (lane == 0) slot = atomicAdd(&cursor[e], 1);
    slot = __shfl(slot, 0, 64);
    if (lane == 0) { stok[slot] = t; sw[slot] = tw[2 * t + j]; }
    unsigned short* dst = Xg + (size_t)slot * D_MODEL + lane * 16;
    *(ushort8*)(dst) = p0;
    *(ushort8*)(dst + 8) = p1;
  }
}

// -------- LDS-tiled transpose+cast: W[e][K][N] f32 -> WT[e][N][K] bf16 ------
// Tile 64(K) x 128(N). Phase1: coalesced f32x4 reads of k-pairs, pack to
// dwords (k even low / k odd high), ds_write_b128 (conflict-free).
// Phase2: ds_read_b32 column walk (2-way on banks = free), 64 B contiguous
// global stores per lane.
__global__ __launch_bounds__(256) void k_trans(
    const float* __restrict__ W, unsigned short* __restrict__ WT,
    int K, int N) {
  __shared__ unsigned Tl[32][132];
  int e = blockIdx.z;
  int n0 = blockIdx.x * 128, k0 = blockIdx.y * 64;
  const float* src = W + (size_t)e * K * N;
  unsigned short* dst = WT + (size_t)e * N * K;
  int t = threadIdx.x;
  int n4 = (t & 31) * 4;
  int kkb = t >> 5;  // 0..7
#pragma unroll
  for (int i = 0; i < 4; i++) {
    int kk = kkb + i * 8;  // 0..31 (k-pair index)
    const float* p0 = src + (size_t)(k0 + 2 * kk) * N + n0 + n4;
    f32x4 a = *(const f32x4*)p0;
    f32x4 b = *(const f32x4*)(p0 + N);
    u32x4 q;
#pragma unroll
    for (int j = 0; j < 4; j++) q[j] = pack2(a[j], b[j]);
    *(u32x4*)&Tl[kk][n4] = q;
  }
  __syncthreads();
  int n = t >> 1, half = t & 1;
  unsigned v[16];
#pragma unroll
  for (int j = 0; j < 16; j++) v[j] = Tl[half * 16 + j][n];
  unsigned short* op = dst + (size_t)(n0 + n) * K + k0 + half * 32;
#pragma unroll
  for (int c = 0; c < 4; c++) {
    u32x4 q = {v[4 * c], v[4 * c + 1], v[4 * c + 2], v[4 * c + 3]};
    *(u32x4*)(op + c * 8) = q;
  }
}

// ============================ FAST-PATH GEMMS ==============================
// 128x128 tile, BK=64, 4 waves x (64x64 via 4x4 16x16x32 MFMA).
// LDS chunk-major: elem (row,k) at [((k>>3)*128+row)*8 + (k&7)]; A and B
// staged with 16B global_load_lds.

__global__ __launch_bounds__(256, 2) void k_gemm1_fast(
    const unsigned short* __restrict__ Xg,
    const unsigned short* __restrict__ WgT,
    const unsigned short* __restrict__ WuT,
    const int* __restrict__ offs, const int* __restrict__ tiles,
    const int* __restrict__ ntiles, unsigned short* __restrict__ H) {
  int td = blockIdx.x >> 5, nt = blockIdx.x & 31;
  if (td >= *ntiles) return;
  int d = tiles[td];
  int e = d & 255, mt = d >> 8;
  int base = offs[e];
  int ne = offs[e + 1] - base;

  __shared__ __align__(16) unsigned short At[8 * 128 * 8];
  __shared__ __align__(16) unsigned short Bg[8 * 128 * 8];
  __shared__ __align__(16) unsigned short Bu[8 * 128 * 8];

  int tid = threadIdx.x;
  int wv = tid >> 6, lane = tid & 63;
  int quad = lane >> 4, lr = lane & 15;
  int rh = (wv >> 1) * 64, ch = (wv & 1) * 64;

  f32x4 accG[4][4], accU[4][4];
#pragma unroll
  for (int i = 0; i < 4; i++)
#pragma unroll
    for (int j = 0; j < 4; j++) {
      accG[i][j] = (f32x4){0.f, 0.f, 0.f, 0.f};
      accU[i][j] = (f32x4){0.f, 0.f, 0.f, 0.f};
    }

  const unsigned short* bgp = WgT + (size_t)e * D_MODEL * HIDDEN +
                              (size_t)(nt * 128) * D_MODEL;
  const unsigned short* bup = WuT + (size_t)e * D_MODEL * HIDDEN +
                              (size_t)(nt * 128) * D_MODEL;

  for (int kt = 0; kt < D_MODEL / 64; kt++) {
#pragma unroll
    for (int s = 0; s < 4; s++) {
      int c = wv * 2 + (s >> 1);
      int h = s & 1;
      int gr = mt * 128 + h * 64 + lane;
      if (gr > ne - 1) gr = ne - 1;
      async_ld16(Xg + (size_t)(base + gr) * D_MODEL + kt * 64 + c * 8,
                 &At[(c * 128 + h * 64) * 8]);
    }
#pragma unroll
    for (int s = 0; s < 4; s++) {
      int c = wv * 2 + (s >> 1);
      int h = s & 1;
      int n = h * 64 + lane;
      async_ld16(bgp + (size_t)n * D_MODEL + kt * 64 + c * 8,
                 &Bg[(c * 128 + h * 64) * 8]);
      async_ld16(bup + (size_t)n * D_MODEL + kt * 64 + c * 8,
                 &Bu[(c * 128 + h * 64) * 8]);
    }
    __syncthreads();
#pragma unroll
    for (int ks = 0; ks < 2; ks++) {
      bf16x8 a[4], bg[4], bu[4];
#pragma unroll
      for (int i = 0; i < 4; i++)
        a[i] = *(const bf16x8*)&At[((ks * 4 + quad) * 128 + rh + i * 16 + lr) * 8];
#pragma unroll
      for (int j = 0; j < 4; j++) {
        bg[j] = *(const bf16x8*)&Bg[((ks * 4 + quad) * 128 + ch + j * 16 + lr) * 8];
        bu[j] = *(const bf16x8*)&Bu[((ks * 4 + quad) * 128 + ch + j * 16 + lr) * 8];
      }
#pragma unroll
      for (int i = 0; i < 4; i++)
#pragma unroll
        for (int j = 0; j < 4; j++) {
          accG[i][j] = __builtin_amdgcn_mfma_f32_16x16x32_bf16(a[i], bg[j], accG[i][j], 0, 0, 0);
          accU[i][j] = __builtin_amdgcn_mfma_f32_16x16x32_bf16(a[i], bu[j], accU[i][j], 0, 0, 0);
        }
    }
    __syncthreads();
  }
#pragma unroll
  for (int i = 0; i < 4; i++)
#pragma unroll
    for (int r = 0; r < 4; r++) {
      int grow = mt * 128 + rh + i * 16 + quad * 4 + r;
      if (grow < ne) {
        size_t rowoff = (size_t)(base + grow) * HIDDEN + (size_t)nt * 128 + ch + lr;
#pragma unroll
        for (int j = 0; j < 4; j++) {
          float g = accG[i][j][r];
          float hv = g / (1.f + __expf(-g)) * accU[i][j][r];
          H[rowoff + j * 16] = f2bf(hv);
        }
      }
    }
}

// split-K=4: each block does K range [sk*1024, +1024), atomic-add epilogue.
__global__ __launch_bounds__(256, 2) void k_gemm2_fast(
    const unsigned short* __restrict__ H,
    const unsigned short* __restrict__ WdT,
    const int* __restrict__ offs, const int* __restrict__ tiles,
    const int* __restrict__ ntiles, const int* __restrict__ stok,
    const float* __restrict__ sw, float* __restrict__ out) {
  int td = blockIdx.x >> 5;
  int r2 = blockIdx.x & 31;
  int nt = r2 >> 2, sk = r2 & 3;
  if (td >= *ntiles) return;
  int d = tiles[td];
  int e = d & 255, mt = d >> 8;
  int base = offs[e];
  int ne = offs[e + 1] - base;

  __shared__ __align__(16) unsigned short At[8 * 128 * 8];
  __shared__ __align__(16) unsigned short Bd[8 * 128 * 8];

  int tid = threadIdx.x;
  int wv = tid >> 6, lane = tid & 63;
  int quad = lane >> 4, lr = lane & 15;
  int rh = (wv >> 1) * 64, ch = (wv & 1) * 64;

  f32x4 acc[4][4];
#pragma unroll
  for (int i = 0; i < 4; i++)
#pragma unroll
    for (int j = 0; j < 4; j++) acc[i][j] = (f32x4){0.f, 0.f, 0.f, 0.f};

  const unsigned short* bdp = WdT + (size_t)e * HIDDEN * D_MODEL +
                              (size_t)(nt * 128) * HIDDEN;

  for (int kt = sk * 16; kt < sk * 16 + 16; kt++) {
#pragma unroll
    for (int s = 0; s < 4; s++) {
      int c = wv * 2 + (s >> 1);
      int h = s & 1;
      int gr = mt * 128 + h * 64 + lane;
      if (gr > ne - 1) gr = ne - 1;
      async_ld16(H + (size_t)(base + gr) * HIDDEN + kt * 64 + c * 8,
                 &At[(c * 128 + h * 64) * 8]);
    }
#pragma unroll
    for (int s = 0; s < 4; s++) {
      int c = wv * 2 + (s >> 1);
      int h = s & 1;
      int n = h * 64 + lane;
      async_ld16(bdp + (size_t)n * HIDDEN + kt * 64 + c * 8,
                 &Bd[(c * 128 + h * 64) * 8]);
    }
    __syncthreads();
#pragma unroll
    for (int ks = 0; ks < 2; ks++) {
      bf16x8 a[4], b[4];
#pragma unroll
      for (int i = 0; i < 4; i++)
        a[i] = *(const bf16x8*)&At[((ks * 4 + quad) * 128 + rh + i * 16 + lr) * 8];
#pragma unroll
      for (int j = 0; j < 4; j++)
        b[j] = *(const bf16x8*)&Bd[((ks * 4 + quad) * 128 + ch + j * 16 + lr) * 8];
#pragma unroll
      for (int i = 0; i < 4; i++)
#pragma unroll
        for (int j = 0; j < 4; j++)
          acc[i][j] = __builtin_amdgcn_mfma_f32_16x16x32_bf16(a[i], b[j], acc[i][j], 0, 0, 0);
    }
    __syncthreads();
  }
#pragma unroll
  for (int i = 0; i < 4; i++)
#pragma unroll
    for (int r = 0; r < 4; r++) {
      int grow = mt * 128 + rh + i * 16 + quad * 4 + r;
      if (grow < ne) {
        int slot = base + grow;
        int t = stok[slot];
        float w = sw[slot];
        float* op = out + (size_t)t * D_MODEL + nt * 128 + ch + lr;
#pragma unroll
        for (int j = 0; j < 4; j++)
          unsafeAtomicAdd(op + j * 16, acc[i][j][r] * w);
      }
    }
}

// ==================== FALLBACK GEMMS (small ws; round-1) ====================
__global__ __launch_bounds__(256, 2) void k_gemm1(
    const unsigned short* __restrict__ Xg,
    const float* __restrict__ Wg, const float* __restrict__ Wu,
    const int* __restrict__ offs, unsigned short* __restrict__ H) {
  int bid = blockIdx.x;
  int e = bid >> 10, mt = (bid >> 5) & 31, nt = bid & 31;
  int base = offs[e];
  int ne = offs[e + 1] - base;
  if (mt * 128 >= ne) return;

  __shared__ __align__(16) unsigned short At[8 * 128 * 8];
  __shared__ __align__(16) unsigned short Bg[8 * 128 * 8];
  __shared__ __align__(16) unsigned short Bu[8 * 128 * 8];

  int tid = threadIdx.x;
  int wv = tid >> 6, lane = tid & 63;
  int quad = lane >> 4, lr = lane & 15;
  int rh = (wv >> 1) * 64, ch = (wv & 1) * 64;

  f32x4 accG[4][4], accU[4][4];
#pragma unroll
  for (int i = 0; i < 4; i++)
#pragma unroll
    for (int j = 0; j < 4; j++) {
      accG[i][j] = (f32x4){0.f, 0.f, 0.f, 0.f};
      accU[i][j] = (f32x4){0.f, 0.f, 0.f, 0.f};
    }

  const float* wgp = Wg + (size_t)e * D_MODEL * HIDDEN + (size_t)nt * 128;
  const float* wup = Wu + (size_t)e * D_MODEL * HIDDEN + (size_t)nt * 128;
  int n4 = tid >> 3;
  int kp0 = tid & 7;

  for (int kt = 0; kt < D_MODEL / 64; kt++) {
#pragma unroll
    for (int s = 0; s < 4; s++) {
      int c = wv * 2 + (s >> 1);
      int h = s & 1;
      int gr = mt * 128 + h * 64 + lane;
      if (gr > ne - 1) gr = ne - 1;
      async_ld16(Xg + (size_t)(base + gr) * D_MODEL + kt * 64 + c * 8,
                 &At[(c * 128 + h * 64) * 8]);
    }
#pragma unroll
    for (int u = 0; u < 4; u++) {
      int kp = kp0 + u * 8;
      const float* pg = wgp + (size_t)(kt * 64 + kp * 2) * HIDDEN + n4 * 4;
      f32x4 g0 = *(const f32x4*)pg;
      f32x4 g1 = *(const f32x4*)(pg + HIDDEN);
      const float* pu = wup + (size_t)(kt * 64 + kp * 2) * HIDDEN + n4 * 4;
      f32x4 u0 = *(const f32x4*)pu;
      f32x4 u1 = *(const f32x4*)(pu + HIDDEN);
      int cB = kp >> 2;
      int ko = (kp & 3) * 2;
#pragma unroll
      for (int j = 0; j < 4; j++) {
        int n = n4 * 4 + j;
        *(unsigned*)&Bg[(cB * 128 + n) * 8 + ko] = pack2(g0[j], g1[j]);
        *(unsigned*)&Bu[(cB * 128 + n) * 8 + ko] = pack2(u0[j], u1[j]);
      }
    }
    __syncthreads();
#pragma unroll
    for (int ks = 0; ks < 2; ks++) {
      bf16x8 a[4], bg[4], bu[4];
#pragma unroll
      for (int i = 0; i < 4; i++)
        a[i] = *(const bf16x8*)&At[((ks * 4 + quad) * 128 + rh + i * 16 + lr) * 8];
#pragma unroll
      for (int j = 0; j < 4; j++) {
        bg[j] = *(const bf16x8*)&Bg[((ks * 4 + quad) * 128 + ch + j * 16 + lr) * 8];
        bu[j] = *(const bf16x8*)&Bu[((ks * 4 + quad) * 128 + ch + j * 16 + lr) * 8];
      }
#pragma unroll
      for (int i = 0; i < 4; i++)
#pragma unroll
        for (int j = 0; j < 4; j++) {
          accG[i][j] = __builtin_amdgcn_mfma_f32_16x16x32_bf16(a[i], bg[j], accG[i][j], 0, 0, 0);
          accU[i][j] = __builtin_amdgcn_mfma_f32_16x16x32_bf16(a[i], bu[j], accU[i][j], 0, 0, 0);
        }
    }
    __syncthreads();
  }
#pragma unroll
  for (int i = 0; i < 4; i++)
#pragma unroll
    for (int r = 0; r < 4; r++) {
      int grow = mt * 128 + rh + i * 16 + quad * 4 + r;
      if (grow < ne) {
        size_t rowoff = (size_t)(base + grow) * HIDDEN + (size_t)nt * 128 + ch + lr;
#pragma unroll
        for (int j = 0; j < 4; j++) {
          float g = accG[i][j][r];
          float hv = g / (1.f + __expf(-g)) * accU[i][j][r];
          H[rowoff + j * 16] = f2bf(hv);
        }
      }
    }
}

__global__ __launch_bounds__(256, 2) void k_gemm2(
    const unsigned short* __restrict__ H, const float* __restrict__ Wd,
    const int* __restrict__ offs, const int* __restrict__ stok,
    const float* __restrict__ sw, float* __restrict__ out) {
  int bid = blockIdx.x;
  int e = bid >> 8, mt = (bid >> 3) & 31, nt = bid & 7;
  int base = offs[e];
  int ne = offs[e + 1] - base;
  if (mt * 128 >= ne) return;

  __shared__ __align__(16) unsigned short At[8 * 128 * 8];
  __shared__ __align__(16) unsigned short Bd[8 * 128 * 8];

  int tid = threadIdx.x;
  int wv = tid >> 6, lane = tid & 63;
  int quad = lane >> 4, lr = lane & 15;
  int rh = (wv >> 1) * 64, ch = (wv & 1) * 64;

  f32x4 acc[4][4];
#pragma unroll
  for (int i = 0; i < 4; i++)
#pragma unroll
    for (int j = 0; j < 4; j++) acc[i][j] = (f32x4){0.f, 0.f, 0.f, 0.f};

  const float* wdp = Wd + (size_t)e * HIDDEN * D_MODEL + (size_t)nt * 128;
  int n4 = tid >> 3;
  int kp0 = tid & 7;

  for (int kt = 0; kt < HIDDEN / 64; kt++) {
#pragma unroll
    for (int s = 0; s < 4; s++) {
      int c = wv * 2 + (s >> 1);
      int h = s & 1;
      int gr = mt * 128 + h * 64 + lane;
      if (gr > ne - 1) gr = ne - 1;
      async_ld16(H + (size_t)(base + gr) * HIDDEN + kt * 64 + c * 8,
                 &At[(c * 128 + h * 64) * 8]);
    }
#pragma unroll
    for (int u = 0; u < 4; u++) {
      int kp = kp0 + u * 8;
      const float* pd = wdp + (size_t)(kt * 64 + kp * 2) * D_MODEL + n4 * 4;
      f32x4 d0 = *(const f32x4*)pd;
      f32x4 d1 = *(const f32x4*)(pd + D_MODEL);
      int cB = kp >> 2;
      int ko = (kp & 3) * 2;
#pragma unroll
      for (int j = 0; j < 4; j++)
        *(unsigned*)&Bd[(cB * 128 + n4 * 4 + j) * 8 + ko] = pack2(d0[j], d1[j]);
    }
    __syncthreads();
#pragma unroll
    for (int ks = 0; ks < 2; ks++) {
      bf16x8 a[4], b[4];
#pragma unroll
      for (int i = 0; i < 4; i++)
        a[i] = *(const bf16x8*)&At[((ks * 4 + quad) * 128 + rh + i * 16 + lr) * 8];
#pragma unroll
      for (int j = 0; j < 4; j++)
        b[j] = *(const bf16x8*)&Bd[((ks * 4 + quad) * 128 + ch + j * 16 + lr) * 8];
#pragma unroll
      for (int i = 0; i < 4; i++)
#pragma unroll
        for (int j = 0; j < 4; j++)
          acc[i][j] = __builtin_amdgcn_mfma_f32_16x16x32_bf16(a[i], b[j], acc[i][j], 0, 0, 0);
    }
    __syncthreads();
  }
#pragma unroll
  for (int i = 0; i < 4; i++)
#pragma unroll
    for (int r = 0; r < 4; r++) {
      int grow = mt * 128 + rh + i * 16 + quad * 4 + r;
      if (grow < ne) {
        int slot = base + grow;
        int t = stok[slot];
        float w = sw[slot];
        float* op = out + (size_t)t * D_MODEL + nt * 128 + ch + lr;
#pragma unroll
        for (int j = 0; j < 4; j++)
          unsafeAtomicAdd(op + j * 16, acc[i][j][r] * w);
      }
    }
}

extern "C" void kernel_launch(void* const* d_in, const int* in_sizes, int n_in,
                              void* d_out, int out_size, void* d_ws, size_t ws_size,
                              hipStream_t stream) {
  const float* x  = (const float*)d_in[0];
  const float* Wg = (const float*)d_in[1];
  const float* Wu = (const float*)d_in[2];
  const float* Wd = (const float*)d_in[3];
  const float* Wr = (const float*)d_in[4];
  float* out = (float*)d_out;

  int* counts = (int*)d_ws;              // [8]
  int* cursor = counts + 8;              // [8]
  int* offs   = counts + 16;             // [9]
  int* ntiles = counts + 25;             // [1]
  int* tiles  = counts + 26;             // [MAXTILE]
  int* te     = counts + 128;            // [2*T]
  float* tw   = (float*)(te + NSLOT);    // [2*T]
  int* stok   = (int*)(tw + NSLOT);      // [2*T]
  float* sw   = (float*)(stok + NSLOT);  // [2*T]
  unsigned short* Xg = (unsigned short*)(sw + NSLOT);   // [8192*1024] bf16
  unsigned short* H  = Xg + (size_t)NSLOT * D_MODEL;    // [8192*4096] bf16
  unsigned short* WgT = H + (size_t)NSLOT * HIDDEN;     // [8*1024*4096] bf16 (n-major)
  unsigned short* WuT = WgT + (size_t)N_EXP * D_MODEL * HIDDEN;
  unsigned short* WdT = WuT + (size_t)N_EXP * D_MODEL * HIDDEN;

  size_t need_slow = (size_t)((char*)WgT - (char*)d_ws);
  size_t need_fast = (size_t)((char*)(WdT + (size_t)N_EXP * HIDDEN * D_MODEL) -
                              (char*)d_ws);

  hipMemsetAsync(out, 0, (size_t)out_size * sizeof(float), stream);
  if (ws_size < need_slow) return;  // clean absmax fail

  hipMemsetAsync(counts, 0, 64, stream);
  k_router<<<T_TOK / 4, 256, 0, stream>>>(x, Wr, counts, te, tw);
  k_scan<<<1, 64, 0, stream>>>(counts, offs, cursor, tiles, ntiles);
  k_gather<<<T_TOK / 4, 256, 0, stream>>>(x, te, tw, cursor, stok, sw, Xg);

  if (ws_size >= need_fast) {
    k_trans<<<dim3(HIDDEN / 128, D_MODEL / 64, N_EXP), 256, 0, stream>>>(
        Wg, WgT, D_MODEL, HIDDEN);
    k_trans<<<dim3(HIDDEN / 128, D_MODEL / 64, N_EXP), 256, 0, stream>>>(
        Wu, WuT, D_MODEL, HIDDEN);
    k_trans<<<dim3(D_MODEL / 128, HIDDEN / 64, N_EXP), 256, 0, stream>>>(
        Wd, WdT, HIDDEN, D_MODEL);
    k_gemm1_fast<<<MAXTILE * 32, 256, 0, stream>>>(Xg, WgT, WuT, offs, tiles,
                                                   ntiles, H);
    k_gemm2_fast<<<MAXTILE * 32, 256, 0, stream>>>(H, WdT, offs, tiles, ntiles,
                                                   stok, sw, out);
  } else {
    k_gemm1<<<N_EXP * 32 * 32, 256, 0, stream>>>(Xg, Wg, Wu, offs, H);
    k_gemm2<<<N_EXP * 32 * 8, 256, 0, stream>>>(H, Wd, offs, stok, sw, out);
  }
}